// Round 1
// baseline (1082.775 us; speedup 1.0000x reference)
//
#include <hip/hip_runtime.h>
#include <math.h>

constexpr int DIN = 256;   // input dim
constexpr int H   = 4;     // heads
constexpr int O   = 64;    // out dim per head
constexpr int HO  = H * O; // 256, also the fused GEMM N-dim and final feature dim

// ---------------------------------------------------------------------------
// Kernel 1: F[n, h*64+o] = x[n,:] @ Ws[h,:,o] + bs[h,o]
// Fused epilogue: a_s[h,n] = sum_o F[n,h*64+o]*aw[h,o]
//                 a_d[h,n] = sum_o F[n,h*64+o]*aw[h,64+o]
// Block = 256 threads (thread t -> col t, h = t>>6, o = t&63), 16 rows/block.
// Each wave (64 threads) covers exactly one head -> shuffle-reduce for a_s/a_d.
// ---------------------------------------------------------------------------
__global__ __launch_bounds__(256) void k_gemm(const float* __restrict__ x,
    const float* __restrict__ Ws, const float* __restrict__ bs,
    const float* __restrict__ aw, int N,
    float* __restrict__ F, float* __restrict__ a_s, float* __restrict__ a_d)
{
    __shared__ float xs[16][DIN];
    const int t = threadIdx.x;
    const int row0 = blockIdx.x * 16;

    // stage 16 rows of x into LDS, coalesced
    #pragma unroll
    for (int i = 0; i < 16; ++i) {
        int r = row0 + i;
        xs[i][t] = (r < N) ? x[(size_t)r * DIN + t] : 0.f;
    }
    __syncthreads();

    const int h = t >> 6;
    const int o = t & 63;
    const int lane = t & 63;
    const float* Wp = Ws + (size_t)h * (DIN * O) + o;  // Ws[h][k][o], step k -> +O

    float acc[16];
    #pragma unroll
    for (int r = 0; r < 16; ++r) acc[r] = 0.f;

    for (int k4 = 0; k4 < DIN; k4 += 4) {
        const float w0 = Wp[(k4 + 0) * O];
        const float w1 = Wp[(k4 + 1) * O];
        const float w2 = Wp[(k4 + 2) * O];
        const float w3 = Wp[(k4 + 3) * O];
        #pragma unroll
        for (int r = 0; r < 16; ++r) {
            const float4 xv = *(const float4*)&xs[r][k4];  // wave-uniform broadcast
            acc[r] = fmaf(xv.x, w0, acc[r]);
            acc[r] = fmaf(xv.y, w1, acc[r]);
            acc[r] = fmaf(xv.z, w2, acc[r]);
            acc[r] = fmaf(xv.w, w3, acc[r]);
        }
    }

    const float b   = bs[t];
    const float aws = aw[h * (2 * O + 1) + o];
    const float awd = aw[h * (2 * O + 1) + O + o];
    const int rmax = min(16, N - row0);
    for (int r = 0; r < rmax; ++r) {
        const int n = row0 + r;
        const float f = acc[r] + b;
        F[(size_t)n * HO + t] = f;
        float ps = f * aws;
        float pd = f * awd;
        #pragma unroll
        for (int off = 32; off > 0; off >>= 1) {
            ps += __shfl_down(ps, off, 64);
            pd += __shfl_down(pd, off, 64);
        }
        if (lane == 0) { a_s[h * N + n] = ps; a_d[h * N + n] = pd; }
    }
}

// ---------------------------------------------------------------------------
// Kernel 2: per-edge scatter. One wave per edge; lane = o, loop over h.
// score[h,e] = a_s[h,src] + a_d[h,dst] + aw[h,128]*elem[e] + ab[h]
// w = exp(-relu(score/20)); out[src, h*64+o] += w * F[dst, h*64+o]
// ---------------------------------------------------------------------------
__global__ __launch_bounds__(256) void k_edge(const int* __restrict__ idx,
    const float* __restrict__ elem, const float* __restrict__ aw,
    const float* __restrict__ ab, const float* __restrict__ F,
    const float* __restrict__ a_s, const float* __restrict__ a_d,
    int N, int E, float* __restrict__ out, float* __restrict__ row_sum)
{
    const int lane = threadIdx.x & 63;
    const int e = blockIdx.x * 4 + (threadIdx.x >> 6);
    if (e >= E) return;

    const int s = idx[e];        // idx[0][e]
    const int d = idx[E + e];    // idx[1][e]
    const float el = elem[e];

    float w[H];
    #pragma unroll
    for (int h = 0; h < H; ++h) {
        const float score = a_s[h * N + s] + a_d[h * N + d]
                          + aw[h * (2 * O + 1) + 2 * O] * el + ab[h];
        w[h] = __expf(-fmaxf(score * 0.05f, 0.f));
        const float fd = F[(size_t)d * HO + h * O + lane];
        unsafeAtomicAdd(&out[(size_t)s * HO + h * O + lane], w[h] * fd);
    }
    if (lane == 0) {
        #pragma unroll
        for (int h = 0; h < H; ++h) unsafeAtomicAdd(&row_sum[h * N + s], w[h]);
    }
}

// ---------------------------------------------------------------------------
// Kernel 3: out[n, h*64+o] /= row_sum[h, n]
// ---------------------------------------------------------------------------
__global__ __launch_bounds__(256) void k_norm(float* __restrict__ out,
    const float* __restrict__ row_sum, int N)
{
    const long long i = (long long)blockIdx.x * 256 + threadIdx.x;
    if (i >= (long long)N * HO) return;
    const int n = (int)(i >> 8);
    const int h = ((int)i & 255) >> 6;
    out[i] = out[i] / row_sum[h * N + n];
}

extern "C" void kernel_launch(void* const* d_in, const int* in_sizes, int n_in,
                              void* d_out, int out_size, void* d_ws, size_t ws_size,
                              hipStream_t stream)
{
    const float* x    = (const float*)d_in[0];
    const int*   idx  = (const int*)d_in[1];
    const float* elem = (const float*)d_in[2];
    const float* Ws   = (const float*)d_in[3];
    const float* bs   = (const float*)d_in[4];
    const float* aw   = (const float*)d_in[5];
    const float* ab   = (const float*)d_in[6];

    const int N = in_sizes[0] / DIN;   // 50000
    const int E = in_sizes[1] / 2;     // 800000

    // workspace layout (fp32): F[N*256] | a_s[H*N] | a_d[H*N] | row_sum[H*N]
    float* F       = (float*)d_ws;
    float* a_s     = F + (size_t)N * HO;
    float* a_d     = a_s + (size_t)H * N;
    float* row_sum = a_d + (size_t)H * N;
    float* out     = (float*)d_out;

    // d_out / ws are poisoned 0xAA before every launch -> zero accumulators
    hipMemsetAsync(d_out, 0, (size_t)out_size * sizeof(float), stream);
    hipMemsetAsync(row_sum, 0, (size_t)H * N * sizeof(float), stream);

    k_gemm<<<(N + 15) / 16, 256, 0, stream>>>(x, Ws, bs, aw, N, F, a_s, a_d);
    k_edge<<<(E + 3) / 4, 256, 0, stream>>>(idx, elem, aw, ab, F, a_s, a_d,
                                            N, E, out, row_sum);
    k_norm<<<((long long)N * HO + 255) / 256, 256, 0, stream>>>(out, row_sum, N);
}

// Round 2
// 535.708 us; speedup vs baseline: 2.0212x; 2.0212x over previous
//
#include <hip/hip_runtime.h>
#include <math.h>

constexpr int DIN = 256;   // input dim
constexpr int H   = 4;     // heads
constexpr int O   = 64;    // out dim per head
constexpr int HO  = H * O; // 256
constexpr int AWS = 2 * O + 1; // aw row stride = 129

// ---------------------------------------------------------------------------
// Kernel 1: F[n, h*64+o] = x[n,:] @ Ws[h,:,o] + bs[h,o]
// Fused: a_s[h,n] = sum_o F*aw[h,o]; a_d[h,n] = sum_o F*aw[h,64+o]
// ---------------------------------------------------------------------------
__global__ __launch_bounds__(256) void k_gemm(const float* __restrict__ x,
    const float* __restrict__ Ws, const float* __restrict__ bs,
    const float* __restrict__ aw, int N,
    float* __restrict__ F, float* __restrict__ a_s, float* __restrict__ a_d)
{
    __shared__ float xs[16][DIN];
    const int t = threadIdx.x;
    const int row0 = blockIdx.x * 16;

    #pragma unroll
    for (int i = 0; i < 16; ++i) {
        int r = row0 + i;
        xs[i][t] = (r < N) ? x[(size_t)r * DIN + t] : 0.f;
    }
    __syncthreads();

    const int h = t >> 6;
    const int o = t & 63;
    const int lane = t & 63;
    const float* Wp = Ws + (size_t)h * (DIN * O) + o;

    float acc[16];
    #pragma unroll
    for (int r = 0; r < 16; ++r) acc[r] = 0.f;

    for (int k4 = 0; k4 < DIN; k4 += 4) {
        const float w0 = Wp[(k4 + 0) * O];
        const float w1 = Wp[(k4 + 1) * O];
        const float w2 = Wp[(k4 + 2) * O];
        const float w3 = Wp[(k4 + 3) * O];
        #pragma unroll
        for (int r = 0; r < 16; ++r) {
            const float4 xv = *(const float4*)&xs[r][k4];
            acc[r] = fmaf(xv.x, w0, acc[r]);
            acc[r] = fmaf(xv.y, w1, acc[r]);
            acc[r] = fmaf(xv.z, w2, acc[r]);
            acc[r] = fmaf(xv.w, w3, acc[r]);
        }
    }

    const float b   = bs[t];
    const float aws = aw[h * AWS + o];
    const float awd = aw[h * AWS + O + o];
    const int rmax = min(16, N - row0);
    for (int r = 0; r < rmax; ++r) {
        const int n = row0 + r;
        const float f = acc[r] + b;
        F[(size_t)n * HO + t] = f;
        float ps = f * aws;
        float pd = f * awd;
        #pragma unroll
        for (int off = 32; off > 0; off >>= 1) {
            ps += __shfl_down(ps, off, 64);
            pd += __shfl_down(pd, off, 64);
        }
        if (lane == 0) { a_s[h * N + n] = ps; a_d[h * N + n] = pd; }
    }
}

// ---------------------------------------------------------------------------
// CSR build: histogram by src
// ---------------------------------------------------------------------------
__global__ __launch_bounds__(256) void k_hist(const int* __restrict__ idx, int E,
                                              int* __restrict__ cnt)
{
    int e = blockIdx.x * 256 + threadIdx.x;
    if (e < E) atomicAdd(&cnt[idx[e]], 1);
}

// ---------------------------------------------------------------------------
// Single-block exclusive scan of cnt[0..N-1] -> row_ptr[0..N]
// 256 threads; each thread owns a contiguous chunk.
// ---------------------------------------------------------------------------
__global__ __launch_bounds__(256) void k_scan(const int* __restrict__ cnt,
                                              int* __restrict__ row_ptr, int N)
{
    __shared__ int wsum[4];
    __shared__ int woff[4];
    const int t = threadIdx.x;
    const int per = (N + 255) / 256;
    const int lo = min(t * per, N);
    const int hi = min(lo + per, N);

    int s = 0;
    for (int i = lo; i < hi; ++i) s += cnt[i];

    // inclusive scan across 256 threads (wave scan + wave offsets)
    const int lane = t & 63, w = t >> 6;
    int v = s;
    #pragma unroll
    for (int off = 1; off < 64; off <<= 1) {
        int u = __shfl_up(v, off, 64);
        if (lane >= off) v += u;
    }
    if (lane == 63) wsum[w] = v;
    __syncthreads();
    if (t == 0) {
        int run = 0;
        #pragma unroll
        for (int i = 0; i < 4; ++i) { woff[i] = run; run += wsum[i]; }
    }
    __syncthreads();

    int run = v - s + woff[w];   // exclusive prefix for this thread's chunk
    for (int i = lo; i < hi; ++i) { row_ptr[i] = run; run += cnt[i]; }
    if (t == 255) row_ptr[N] = woff[3] + wsum[3];
}

// ---------------------------------------------------------------------------
// Scatter edges into CSR slots; precompute per-head weights.
// ---------------------------------------------------------------------------
__global__ __launch_bounds__(256) void k_scatter(const int* __restrict__ idx,
    const float* __restrict__ elem, const float* __restrict__ aw,
    const float* __restrict__ ab, const float* __restrict__ a_s,
    const float* __restrict__ a_d, int N, int E, int* __restrict__ cursor,
    int* __restrict__ csr_dst, float4* __restrict__ csr_w)
{
    int e = blockIdx.x * 256 + threadIdx.x;
    if (e >= E) return;
    const int s = idx[e];
    const int d = idx[E + e];
    const float el = elem[e];

    float4 w;
    float* wp = (float*)&w;
    #pragma unroll
    for (int h = 0; h < H; ++h) {
        const float score = a_s[h * N + s] + a_d[h * N + d]
                          + aw[h * AWS + 2 * O] * el + ab[h];
        wp[h] = __expf(-fmaxf(score * 0.05f, 0.f));
    }
    const int pos = atomicAdd(&cursor[s], 1);
    csr_dst[pos] = d;
    csr_w[pos] = w;
}

// ---------------------------------------------------------------------------
// Gather: one block per node. Thread t owns output column t (h = t>>6).
// acc[t] = sum_e w[h]*F[dst_e, t];  rs = sum_e w[h];  out = acc/rs.
// ---------------------------------------------------------------------------
__global__ __launch_bounds__(256) void k_gather(const int* __restrict__ row_ptr,
    const int* __restrict__ csr_dst, const float4* __restrict__ csr_w,
    const float* __restrict__ F, float* __restrict__ out, int N)
{
    __shared__ int   s_dst[128];
    __shared__ float4 s_w[128];
    const int n = blockIdx.x;
    const int t = threadIdx.x;
    const int h = t >> 6;
    const int beg = row_ptr[n];
    const int end = row_ptr[n + 1];

    float acc = 0.f;
    float rs  = 0.f;
    for (int base = beg; base < end; base += 128) {
        const int cnt = min(128, end - base);
        __syncthreads();
        if (t < cnt) { s_dst[t] = csr_dst[base + t]; s_w[t] = csr_w[base + t]; }
        __syncthreads();
        for (int j = 0; j < cnt; ++j) {
            const int d = s_dst[j];
            const float w = ((const float*)&s_w[j])[h];   // LDS broadcast
            acc = fmaf(w, F[(size_t)d * HO + t], acc);
            rs += w;
        }
    }
    out[(size_t)n * HO + t] = acc / rs;
}

extern "C" void kernel_launch(void* const* d_in, const int* in_sizes, int n_in,
                              void* d_out, int out_size, void* d_ws, size_t ws_size,
                              hipStream_t stream)
{
    const float* x    = (const float*)d_in[0];
    const int*   idx  = (const int*)d_in[1];
    const float* elem = (const float*)d_in[2];
    const float* Ws   = (const float*)d_in[3];
    const float* bs   = (const float*)d_in[4];
    const float* aw   = (const float*)d_in[5];
    const float* ab   = (const float*)d_in[6];

    const int N = in_sizes[0] / DIN;   // 50000
    const int E = in_sizes[1] / 2;     // 800000

    // workspace layout (fp32/int32):
    // F[N*256] | a_s[H*N] | a_d[H*N] | cnt[N] | row_ptr[N+1] | cursor[N]
    // | csr_dst[E] | csr_w[E]{float4}
    float* F       = (float*)d_ws;
    float* a_s     = F + (size_t)N * HO;
    float* a_d     = a_s + (size_t)H * N;
    int*   cnt     = (int*)(a_d + (size_t)H * N);
    int*   row_ptr = cnt + N;
    int*   cursor  = row_ptr + (N + 1);
    int*   csr_dst = cursor + N;
    // align float4 array to 16B
    size_t off = (size_t)(csr_dst + E) - (size_t)d_ws;
    off = (off + 15) & ~(size_t)15;
    float4* csr_w  = (float4*)((char*)d_ws + off);
    float* out     = (float*)d_out;

    hipMemsetAsync(cnt, 0, (size_t)N * sizeof(int), stream);

    k_gemm<<<(N + 15) / 16, 256, 0, stream>>>(x, Ws, bs, aw, N, F, a_s, a_d);
    k_hist<<<(E + 255) / 256, 256, 0, stream>>>(idx, E, cnt);
    k_scan<<<1, 256, 0, stream>>>(cnt, row_ptr, N);
    hipMemcpyAsync(cursor, row_ptr, (size_t)N * sizeof(int),
                   hipMemcpyDeviceToDevice, stream);
    k_scatter<<<(E + 255) / 256, 256, 0, stream>>>(idx, elem, aw, ab, a_s, a_d,
                                                   N, E, cursor, csr_dst, csr_w);
    k_gather<<<N, 256, 0, stream>>>(row_ptr, csr_dst, csr_w, F, out, N);
}

// Round 3
// 421.446 us; speedup vs baseline: 2.5692x; 1.2711x over previous
//
#include <hip/hip_runtime.h>
#include <math.h>

constexpr int DIN = 256;   // input dim
constexpr int H   = 4;     // heads
constexpr int O   = 64;    // out dim per head
constexpr int HO  = H * O; // 256
constexpr int AWS = 2 * O + 1; // aw row stride = 129

typedef __bf16 bf16x8 __attribute__((ext_vector_type(8)));
typedef float  f32x4  __attribute__((ext_vector_type(4)));

// ---------------------------------------------------------------------------
// Prep: Bt[n][k] = Ws[h=n>>6][k][o=n&63] as bf16. 256x256 = 65536 elements.
// thread -> k = idx&255, n = idx>>8 (coalesced 2B writes along k).
// ---------------------------------------------------------------------------
__global__ __launch_bounds__(256) void k_prep(const float* __restrict__ Ws,
                                              __bf16* __restrict__ Bt)
{
    const int idx = blockIdx.x * 256 + threadIdx.x;
    const int k = idx & 255;
    const int n = idx >> 8;
    Bt[n * 256 + k] = (__bf16)Ws[(n >> 6) * (DIN * O) + k * O + (n & 63)];
}

// ---------------------------------------------------------------------------
// Kernel 1 (MFMA): F[n, t] = x[n,:] @ Bt[t,:]^T + bs[t]   (t = h*64+o)
// Block: 256 thr = 4 waves; 64 rows x 256 cols. Wave w covers cols [w*64, w*64+64)
// == head w. 4x4 tiles of 16x16x32 bf16 MFMA, fp32 accumulate.
// Fused epilogue: a_s[h,n], a_d[h,n] via 16-lane shfl_xor reduction.
// ---------------------------------------------------------------------------
__global__ __launch_bounds__(256) void k_gemm(const float* __restrict__ x,
    const __bf16* __restrict__ Bt, const float* __restrict__ bs,
    const float* __restrict__ aw, int N,
    float* __restrict__ F, float* __restrict__ a_s, float* __restrict__ a_d)
{
    __shared__ __bf16 As[64][DIN + 8];   // +8 bf16 pad -> row stride 132 dwords
    const int t    = threadIdx.x;
    const int w    = t >> 6;          // wave id == head id == col block
    const int lane = t & 63;
    const int c15  = lane & 15;
    const int quad = lane >> 4;
    const int n0   = blockIdx.x * 64;

    // stage 64 rows of x -> bf16 LDS (each wave loads full rows, 4 rows/iter)
    #pragma unroll
    for (int i = 0; i < 16; ++i) {
        const int r   = i * 4 + w;
        const int row = n0 + r;
        float4 xv = make_float4(0.f, 0.f, 0.f, 0.f);
        if (row < N) xv = *(const float4*)&x[(size_t)row * DIN + lane * 4];
        __bf16* dst = &As[r][lane * 4];
        dst[0] = (__bf16)xv.x; dst[1] = (__bf16)xv.y;
        dst[2] = (__bf16)xv.z; dst[3] = (__bf16)xv.w;
    }
    __syncthreads();

    f32x4 acc[4][4] = {};                       // [row_tile][col_tile]
    const __bf16* BtW = Bt + (size_t)(w * 64) * 256;
    const int kq = quad * 8;

    #pragma unroll
    for (int k0 = 0; k0 < DIN; k0 += 32) {
        bf16x8 afr[4], bfr[4];
        #pragma unroll
        for (int rt = 0; rt < 4; ++rt)
            afr[rt] = *(const bf16x8*)&As[rt * 16 + c15][k0 + kq];
        #pragma unroll
        for (int ct = 0; ct < 4; ++ct)
            bfr[ct] = *(const bf16x8*)&BtW[(size_t)(ct * 16 + c15) * 256 + k0 + kq];
        #pragma unroll
        for (int rt = 0; rt < 4; ++rt)
            #pragma unroll
            for (int ct = 0; ct < 4; ++ct)
                acc[rt][ct] = __builtin_amdgcn_mfma_f32_16x16x32_bf16(
                    afr[rt], bfr[ct], acc[rt][ct], 0, 0, 0);
    }

    // epilogue: add bias, store F, fused a_s/a_d
    const int h = w;
    float bsv[4], awsv[4], awdv[4];
    #pragma unroll
    for (int ct = 0; ct < 4; ++ct) {
        const int col = ct * 16 + c15;
        bsv[ct]  = bs[w * 64 + col];
        awsv[ct] = aw[h * AWS + col];
        awdv[ct] = aw[h * AWS + O + col];
    }

    #pragma unroll
    for (int rt = 0; rt < 4; ++rt) {
        float psum[4] = {0.f, 0.f, 0.f, 0.f};
        float pdum[4] = {0.f, 0.f, 0.f, 0.f};
        #pragma unroll
        for (int ct = 0; ct < 4; ++ct) {
            #pragma unroll
            for (int reg = 0; reg < 4; ++reg) {
                const float f = acc[rt][ct][reg] + bsv[ct];
                const int row = n0 + rt * 16 + quad * 4 + reg;
                if (row < N)
                    F[(size_t)row * HO + w * 64 + ct * 16 + c15] = f;
                psum[reg] = fmaf(f, awsv[ct], psum[reg]);
                pdum[reg] = fmaf(f, awdv[ct], pdum[reg]);
            }
        }
        #pragma unroll
        for (int reg = 0; reg < 4; ++reg) {
            float v = psum[reg], u = pdum[reg];
            #pragma unroll
            for (int off = 1; off < 16; off <<= 1) {
                v += __shfl_xor(v, off, 64);
                u += __shfl_xor(u, off, 64);
            }
            const int row = n0 + rt * 16 + quad * 4 + reg;
            if (c15 == 0 && row < N) {
                a_s[h * N + row] = v;
                a_d[h * N + row] = u;
            }
        }
    }
}

// ---------------------------------------------------------------------------
// CSR build: histogram by src
// ---------------------------------------------------------------------------
__global__ __launch_bounds__(256) void k_hist(const int* __restrict__ idx, int E,
                                              int* __restrict__ cnt)
{
    int e = blockIdx.x * 256 + threadIdx.x;
    if (e < E) atomicAdd(&cnt[idx[e]], 1);
}

// ---------------------------------------------------------------------------
// Single-block exclusive scan of cnt[0..N-1] -> row_ptr[0..N]
// ---------------------------------------------------------------------------
__global__ __launch_bounds__(256) void k_scan(const int* __restrict__ cnt,
                                              int* __restrict__ row_ptr, int N)
{
    __shared__ int wsum[4];
    __shared__ int woff[4];
    const int t = threadIdx.x;
    const int per = (N + 255) / 256;
    const int lo = min(t * per, N);
    const int hi = min(lo + per, N);

    int s = 0;
    for (int i = lo; i < hi; ++i) s += cnt[i];

    const int lane = t & 63, w = t >> 6;
    int v = s;
    #pragma unroll
    for (int off = 1; off < 64; off <<= 1) {
        int u = __shfl_up(v, off, 64);
        if (lane >= off) v += u;
    }
    if (lane == 63) wsum[w] = v;
    __syncthreads();
    if (t == 0) {
        int run = 0;
        #pragma unroll
        for (int i = 0; i < 4; ++i) { woff[i] = run; run += wsum[i]; }
    }
    __syncthreads();

    int run = v - s + woff[w];
    for (int i = lo; i < hi; ++i) { row_ptr[i] = run; run += cnt[i]; }
    if (t == 255) row_ptr[N] = woff[3] + wsum[3];
}

// ---------------------------------------------------------------------------
// Scatter edges into CSR slots; precompute per-head weights.
// ---------------------------------------------------------------------------
__global__ __launch_bounds__(256) void k_scatter(const int* __restrict__ idx,
    const float* __restrict__ elem, const float* __restrict__ aw,
    const float* __restrict__ ab, const float* __restrict__ a_s,
    const float* __restrict__ a_d, int N, int E, int* __restrict__ cursor,
    int* __restrict__ csr_dst, float4* __restrict__ csr_w)
{
    int e = blockIdx.x * 256 + threadIdx.x;
    if (e >= E) return;
    const int s = idx[e];
    const int d = idx[E + e];
    const float el = elem[e];

    float4 w;
    float* wp = (float*)&w;
    #pragma unroll
    for (int h = 0; h < H; ++h) {
        const float score = a_s[h * N + s] + a_d[h * N + d]
                          + aw[h * AWS + 2 * O] * el + ab[h];
        wp[h] = __expf(-fmaxf(score * 0.05f, 0.f));
    }
    const int pos = atomicAdd(&cursor[s], 1);
    csr_dst[pos] = d;
    csr_w[pos] = w;
}

// ---------------------------------------------------------------------------
// Gather: one block per node. Thread t owns output column t (h = t>>6).
// ---------------------------------------------------------------------------
__global__ __launch_bounds__(256) void k_gather(const int* __restrict__ row_ptr,
    const int* __restrict__ csr_dst, const float4* __restrict__ csr_w,
    const float* __restrict__ F, float* __restrict__ out, int N)
{
    __shared__ int    s_dst[128];
    __shared__ float4 s_w[128];
    const int n = blockIdx.x;
    const int t = threadIdx.x;
    const int h = t >> 6;
    const int beg = row_ptr[n];
    const int end = row_ptr[n + 1];

    float acc = 0.f;
    float rs  = 0.f;
    for (int base = beg; base < end; base += 128) {
        const int cnt = min(128, end - base);
        __syncthreads();
        if (t < cnt) { s_dst[t] = csr_dst[base + t]; s_w[t] = csr_w[base + t]; }
        __syncthreads();
        for (int j = 0; j < cnt; ++j) {
            const int d = s_dst[j];
            const float w = ((const float*)&s_w[j])[h];
            acc = fmaf(w, F[(size_t)d * HO + t], acc);
            rs += w;
        }
    }
    out[(size_t)n * HO + t] = acc / rs;
}

extern "C" void kernel_launch(void* const* d_in, const int* in_sizes, int n_in,
                              void* d_out, int out_size, void* d_ws, size_t ws_size,
                              hipStream_t stream)
{
    const float* x    = (const float*)d_in[0];
    const int*   idx  = (const int*)d_in[1];
    const float* elem = (const float*)d_in[2];
    const float* Ws   = (const float*)d_in[3];
    const float* bs   = (const float*)d_in[4];
    const float* aw   = (const float*)d_in[5];
    const float* ab   = (const float*)d_in[6];

    const int N = in_sizes[0] / DIN;   // 50000
    const int E = in_sizes[1] / 2;     // 800000

    // ws layout: F[N*256] | a_s[H*N] | a_d[H*N] | cnt[N] | row_ptr[N+1] |
    //            cursor[N] | csr_dst[E] | csr_w[E]{float4} | Bt[256*256]{bf16}
    float* F       = (float*)d_ws;
    float* a_s     = F + (size_t)N * HO;
    float* a_d     = a_s + (size_t)H * N;
    int*   cnt     = (int*)(a_d + (size_t)H * N);
    int*   row_ptr = cnt + N;
    int*   cursor  = row_ptr + (N + 1);
    int*   csr_dst = cursor + N;
    size_t off = (size_t)((char*)(csr_dst + E) - (char*)d_ws);
    off = (off + 15) & ~(size_t)15;
    float4* csr_w  = (float4*)((char*)d_ws + off);
    __bf16* Bt     = (__bf16*)(csr_w + E);
    float* out     = (float*)d_out;

    hipMemsetAsync(cnt, 0, (size_t)N * sizeof(int), stream);

    k_prep<<<(HO * DIN) / 256, 256, 0, stream>>>(Ws, Bt);
    k_gemm<<<(N + 63) / 64, 256, 0, stream>>>(x, Bt, bs, aw, N, F, a_s, a_d);
    k_hist<<<(E + 255) / 256, 256, 0, stream>>>(idx, E, cnt);
    k_scan<<<1, 256, 0, stream>>>(cnt, row_ptr, N);
    hipMemcpyAsync(cursor, row_ptr, (size_t)N * sizeof(int),
                   hipMemcpyDeviceToDevice, stream);
    k_scatter<<<(E + 255) / 256, 256, 0, stream>>>(idx, elem, aw, ab, a_s, a_d,
                                                   N, E, cursor, csr_dst, csr_w);
    k_gather<<<N, 256, 0, stream>>>(row_ptr, csr_dst, csr_w, F, out, N);
}

// Round 4
// 402.527 us; speedup vs baseline: 2.6899x; 1.0470x over previous
//
#include <hip/hip_runtime.h>
#include <math.h>

constexpr int DIN = 256;   // input dim
constexpr int H   = 4;     // heads
constexpr int O   = 64;    // out dim per head
constexpr int HO  = H * O; // 256
constexpr int AWS = 2 * O + 1; // aw row stride = 129

typedef __bf16 bf16x8 __attribute__((ext_vector_type(8)));
typedef float  f32x4  __attribute__((ext_vector_type(4)));

// ---------------------------------------------------------------------------
// Prep: Bt[n][k] = Ws[h=n>>6][k][o=n&63] as bf16. 256x256.
// ---------------------------------------------------------------------------
__global__ __launch_bounds__(256) void k_prep(const float* __restrict__ Ws,
                                              __bf16* __restrict__ Bt)
{
    const int idx = blockIdx.x * 256 + threadIdx.x;
    const int k = idx & 255;
    const int n = idx >> 8;
    Bt[n * 256 + k] = (__bf16)Ws[(n >> 6) * (DIN * O) + k * O + (n & 63)];
}

// ---------------------------------------------------------------------------
// Kernel 1 (MFMA): F[n,t] = x[n,:] @ Bt[t,:]^T + bs[t], stored as bf16.
// Fused epilogue -> a_sT[n*4+h], a_dT[n*4+h] (fp32).
// ---------------------------------------------------------------------------
__global__ __launch_bounds__(256) void k_gemm(const float* __restrict__ x,
    const __bf16* __restrict__ Bt, const float* __restrict__ bs,
    const float* __restrict__ aw, int N,
    __bf16* __restrict__ F, float* __restrict__ a_sT, float* __restrict__ a_dT)
{
    __shared__ __bf16 As[64][DIN + 8];
    const int t    = threadIdx.x;
    const int w    = t >> 6;          // wave id == head id == col block
    const int lane = t & 63;
    const int c15  = lane & 15;
    const int quad = lane >> 4;
    const int n0   = blockIdx.x * 64;

    #pragma unroll
    for (int i = 0; i < 16; ++i) {
        const int r   = i * 4 + w;
        const int row = n0 + r;
        float4 xv = make_float4(0.f, 0.f, 0.f, 0.f);
        if (row < N) xv = *(const float4*)&x[(size_t)row * DIN + lane * 4];
        __bf16* dst = &As[r][lane * 4];
        dst[0] = (__bf16)xv.x; dst[1] = (__bf16)xv.y;
        dst[2] = (__bf16)xv.z; dst[3] = (__bf16)xv.w;
    }
    __syncthreads();

    f32x4 acc[4][4] = {};
    const __bf16* BtW = Bt + (size_t)(w * 64) * 256;
    const int kq = quad * 8;

    #pragma unroll
    for (int k0 = 0; k0 < DIN; k0 += 32) {
        bf16x8 afr[4], bfr[4];
        #pragma unroll
        for (int rt = 0; rt < 4; ++rt)
            afr[rt] = *(const bf16x8*)&As[rt * 16 + c15][k0 + kq];
        #pragma unroll
        for (int ct = 0; ct < 4; ++ct)
            bfr[ct] = *(const bf16x8*)&BtW[(size_t)(ct * 16 + c15) * 256 + k0 + kq];
        #pragma unroll
        for (int rt = 0; rt < 4; ++rt)
            #pragma unroll
            for (int ct = 0; ct < 4; ++ct)
                acc[rt][ct] = __builtin_amdgcn_mfma_f32_16x16x32_bf16(
                    afr[rt], bfr[ct], acc[rt][ct], 0, 0, 0);
    }

    const int h = w;
    float bsv[4], awsv[4], awdv[4];
    #pragma unroll
    for (int ct = 0; ct < 4; ++ct) {
        const int col = ct * 16 + c15;
        bsv[ct]  = bs[w * 64 + col];
        awsv[ct] = aw[h * AWS + col];
        awdv[ct] = aw[h * AWS + O + col];
    }

    #pragma unroll
    for (int rt = 0; rt < 4; ++rt) {
        float psum[4] = {0.f, 0.f, 0.f, 0.f};
        float pdum[4] = {0.f, 0.f, 0.f, 0.f};
        #pragma unroll
        for (int ct = 0; ct < 4; ++ct) {
            #pragma unroll
            for (int reg = 0; reg < 4; ++reg) {
                const float f = acc[rt][ct][reg] + bsv[ct];
                const int row = n0 + rt * 16 + quad * 4 + reg;
                if (row < N)
                    F[(size_t)row * HO + w * 64 + ct * 16 + c15] = (__bf16)f;
                psum[reg] = fmaf(f, awsv[ct], psum[reg]);
                pdum[reg] = fmaf(f, awdv[ct], pdum[reg]);
            }
        }
        #pragma unroll
        for (int reg = 0; reg < 4; ++reg) {
            float v = psum[reg], u = pdum[reg];
            #pragma unroll
            for (int off = 1; off < 16; off <<= 1) {
                v += __shfl_xor(v, off, 64);
                u += __shfl_xor(u, off, 64);
            }
            const int row = n0 + rt * 16 + quad * 4 + reg;
            if (c15 == 0 && row < N) {
                a_sT[row * H + h] = v;
                a_dT[row * H + h] = u;
            }
        }
    }
}

// ---------------------------------------------------------------------------
// CSR build: histogram by src
// ---------------------------------------------------------------------------
__global__ __launch_bounds__(256) void k_hist(const int* __restrict__ idx, int E,
                                              int* __restrict__ cnt)
{
    int e = blockIdx.x * 256 + threadIdx.x;
    if (e < E) atomicAdd(&cnt[idx[e]], 1);
}

// ---------------------------------------------------------------------------
// Single-block (1024 thr) exclusive scan of cnt -> row_ptr[0..N]
// ---------------------------------------------------------------------------
__global__ __launch_bounds__(1024) void k_scan(const int* __restrict__ cnt,
                                               int* __restrict__ row_ptr, int N)
{
    __shared__ int wsum[16];
    __shared__ int woff[16];
    const int t = threadIdx.x;
    const int per = (N + 1023) / 1024;
    const int lo = min(t * per, N);
    const int hi = min(lo + per, N);

    int s = 0;
    for (int i = lo; i < hi; ++i) s += cnt[i];

    const int lane = t & 63, w = t >> 6;
    int v = s;
    #pragma unroll
    for (int off = 1; off < 64; off <<= 1) {
        int u = __shfl_up(v, off, 64);
        if (lane >= off) v += u;
    }
    if (lane == 63) wsum[w] = v;
    __syncthreads();
    if (t == 0) {
        int run = 0;
        #pragma unroll
        for (int i = 0; i < 16; ++i) { woff[i] = run; run += wsum[i]; }
    }
    __syncthreads();

    int run = v - s + woff[w];
    for (int i = lo; i < hi; ++i) { row_ptr[i] = run; run += cnt[i]; }
    if (t == 1023) row_ptr[N] = woff[15] + wsum[15];
}

// ---------------------------------------------------------------------------
// Scatter edges into CSR slots: record = (dst, elem) packed in int2.
// ---------------------------------------------------------------------------
__global__ __launch_bounds__(256) void k_scatter(const int* __restrict__ idx,
    const float* __restrict__ elem, int E, int* __restrict__ cursor,
    int2* __restrict__ csr)
{
    int e = blockIdx.x * 256 + threadIdx.x;
    if (e >= E) return;
    const int s = idx[e];
    const int d = idx[E + e];
    const int pos = atomicAdd(&cursor[s], 1);
    csr[pos] = make_int2(d, __float_as_int(elem[e]));
}

// ---------------------------------------------------------------------------
// Gather: one block per node n. Thread t owns output column t (h = t>>6).
// Stage 128 (dst,elem) records -> compute 4 head-weights/edge in LDS ->
// acc += w[h] * (float)Fb[dst, t];  out = acc / rs.
// ---------------------------------------------------------------------------
__global__ __launch_bounds__(256) void k_gather(const int* __restrict__ row_ptr,
    const int2* __restrict__ csr, const float* __restrict__ a_sT,
    const float* __restrict__ a_dT, const float* __restrict__ aw,
    const float* __restrict__ ab, const __bf16* __restrict__ F,
    float* __restrict__ out, int N)
{
    __shared__ int2  s_rec[128];
    __shared__ float s_w[128][4];
    __shared__ float s_as[4], s_awe[4], s_ab[4];

    const int n = blockIdx.x;
    const int t = threadIdx.x;
    const int h = t >> 6;
    const int beg = row_ptr[n];
    const int end = row_ptr[n + 1];

    if (t < 4) {
        s_as[t]  = a_sT[n * H + t];
        s_awe[t] = aw[t * AWS + 2 * O];
        s_ab[t]  = ab[t];
    }

    float acc = 0.f;
    float rs  = 0.f;
    for (int base = beg; base < end; base += 128) {
        const int cnt = min(128, end - base);
        __syncthreads();
        if (t < cnt) s_rec[t] = csr[base + t];
        __syncthreads();
        // 4 weights per edge; values v = t, t+256 cover cnt*4 <= 512
        #pragma unroll
        for (int v = t; v < cnt * 4; v += 256) {
            const int j  = v >> 2;
            const int hh = v & 3;
            const int d  = s_rec[j].x;
            const float el = __int_as_float(s_rec[j].y);
            const float score = s_as[hh] + a_dT[d * H + hh]
                              + s_awe[hh] * el + s_ab[hh];
            s_w[j][hh] = __expf(-fmaxf(score * 0.05f, 0.f));
        }
        __syncthreads();
        for (int j = 0; j < cnt; ++j) {
            const int d = s_rec[j].x;
            const float w = s_w[j][h];
            acc = fmaf(w, (float)F[(size_t)d * HO + t], acc);
            rs += w;
        }
    }
    out[(size_t)n * HO + t] = acc / rs;
}

extern "C" void kernel_launch(void* const* d_in, const int* in_sizes, int n_in,
                              void* d_out, int out_size, void* d_ws, size_t ws_size,
                              hipStream_t stream)
{
    const float* x    = (const float*)d_in[0];
    const int*   idx  = (const int*)d_in[1];
    const float* elem = (const float*)d_in[2];
    const float* Ws   = (const float*)d_in[3];
    const float* bs   = (const float*)d_in[4];
    const float* aw   = (const float*)d_in[5];
    const float* ab   = (const float*)d_in[6];

    const int N = in_sizes[0] / DIN;   // 50000
    const int E = in_sizes[1] / 2;     // 800000

    // ws layout: F[N*256]{bf16} | a_sT[N*4] | a_dT[N*4] | cnt[N] |
    //            row_ptr[N+1] | cursor[N] | csr[E]{int2} | Bt[256*256]{bf16}
    __bf16* F      = (__bf16*)d_ws;
    float* a_sT    = (float*)(F + (size_t)N * HO);
    float* a_dT    = a_sT + (size_t)N * H;
    int*   cnt     = (int*)(a_dT + (size_t)N * H);
    int*   row_ptr = cnt + N;
    int*   cursor  = row_ptr + (N + 1);
    size_t off = (size_t)((char*)(cursor + N) - (char*)d_ws);
    off = (off + 7) & ~(size_t)7;
    int2*  csr     = (int2*)((char*)d_ws + off);
    __bf16* Bt     = (__bf16*)(csr + E);
    float* out     = (float*)d_out;

    hipMemsetAsync(cnt, 0, (size_t)N * sizeof(int), stream);

    k_prep<<<(HO * DIN) / 256, 256, 0, stream>>>(Ws, Bt);
    k_gemm<<<(N + 63) / 64, 256, 0, stream>>>(x, Bt, bs, aw, N, F, a_sT, a_dT);
    k_hist<<<(E + 255) / 256, 256, 0, stream>>>(idx, E, cnt);
    k_scan<<<1, 1024, 0, stream>>>(cnt, row_ptr, N);
    hipMemcpyAsync(cursor, row_ptr, (size_t)N * sizeof(int),
                   hipMemcpyDeviceToDevice, stream);
    k_scatter<<<(E + 255) / 256, 256, 0, stream>>>(idx, elem, E, cursor, csr);
    k_gather<<<N, 256, 0, stream>>>(row_ptr, csr, a_sT, a_dT, aw, ab, F, out, N);
}

// Round 5
// 340.506 us; speedup vs baseline: 3.1799x; 1.1821x over previous
//
#include <hip/hip_runtime.h>
#include <math.h>

constexpr int DIN = 256;   // input dim
constexpr int H   = 4;     // heads
constexpr int O   = 64;    // out dim per head
constexpr int HO  = H * O; // 256
constexpr int AWS = 2 * O + 1; // aw row stride = 129

typedef __bf16 bf16x8 __attribute__((ext_vector_type(8)));
typedef float  f32x4  __attribute__((ext_vector_type(4)));

__device__ __forceinline__ float bf2f(unsigned short u) {
    union { unsigned int i; float f; } c;
    c.i = ((unsigned int)u) << 16;
    return c.f;
}

// ---------------------------------------------------------------------------
// Fused prep + hist.
// Blocks [0,256): Bt[n][k] = Ws[h=n>>6][k][o=n&63] as bf16 (256x256).
// Blocks [256, ...): histogram by src; rank[e] = arrival order within src row.
// ---------------------------------------------------------------------------
__global__ __launch_bounds__(256) void k_prep_hist(const float* __restrict__ Ws,
    __bf16* __restrict__ Bt, const int* __restrict__ idx, int E,
    int* __restrict__ cnt, int* __restrict__ rank)
{
    const int b = blockIdx.x;
    if (b < 256) {
        const int i = b * 256 + threadIdx.x;
        const int k = i & 255;
        const int n = i >> 8;
        Bt[n * 256 + k] = (__bf16)Ws[(n >> 6) * (DIN * O) + k * O + (n & 63)];
    } else {
        const int e = (b - 256) * 256 + threadIdx.x;
        if (e < E) rank[e] = atomicAdd(&cnt[idx[e]], 1);
    }
}

// ---------------------------------------------------------------------------
// Kernel 1 (MFMA): F[n,t] = x[n,:] @ Bt[t,:]^T + bs[t], stored as bf16.
// Fused epilogue -> a_sT[n*4+h], a_dT[n*4+h] (fp32).
// ---------------------------------------------------------------------------
__global__ __launch_bounds__(256) void k_gemm(const float* __restrict__ x,
    const __bf16* __restrict__ Bt, const float* __restrict__ bs,
    const float* __restrict__ aw, int N,
    __bf16* __restrict__ F, float* __restrict__ a_sT, float* __restrict__ a_dT)
{
    __shared__ __bf16 As[64][DIN + 8];
    const int t    = threadIdx.x;
    const int w    = t >> 6;          // wave id == head id == col block
    const int lane = t & 63;
    const int c15  = lane & 15;
    const int quad = lane >> 4;
    const int n0   = blockIdx.x * 64;

    #pragma unroll
    for (int i = 0; i < 16; ++i) {
        const int r   = i * 4 + w;
        const int row = n0 + r;
        float4 xv = make_float4(0.f, 0.f, 0.f, 0.f);
        if (row < N) xv = *(const float4*)&x[(size_t)row * DIN + lane * 4];
        __bf16* dst = &As[r][lane * 4];
        dst[0] = (__bf16)xv.x; dst[1] = (__bf16)xv.y;
        dst[2] = (__bf16)xv.z; dst[3] = (__bf16)xv.w;
    }
    __syncthreads();

    f32x4 acc[4][4] = {};
    const __bf16* BtW = Bt + (size_t)(w * 64) * 256;
    const int kq = quad * 8;

    #pragma unroll
    for (int k0 = 0; k0 < DIN; k0 += 32) {
        bf16x8 afr[4], bfr[4];
        #pragma unroll
        for (int rt = 0; rt < 4; ++rt)
            afr[rt] = *(const bf16x8*)&As[rt * 16 + c15][k0 + kq];
        #pragma unroll
        for (int ct = 0; ct < 4; ++ct)
            bfr[ct] = *(const bf16x8*)&BtW[(size_t)(ct * 16 + c15) * 256 + k0 + kq];
        #pragma unroll
        for (int rt = 0; rt < 4; ++rt)
            #pragma unroll
            for (int ct = 0; ct < 4; ++ct)
                acc[rt][ct] = __builtin_amdgcn_mfma_f32_16x16x32_bf16(
                    afr[rt], bfr[ct], acc[rt][ct], 0, 0, 0);
    }

    const int h = w;
    float bsv[4], awsv[4], awdv[4];
    #pragma unroll
    for (int ct = 0; ct < 4; ++ct) {
        const int col = ct * 16 + c15;
        bsv[ct]  = bs[w * 64 + col];
        awsv[ct] = aw[h * AWS + col];
        awdv[ct] = aw[h * AWS + O + col];
    }

    #pragma unroll
    for (int rt = 0; rt < 4; ++rt) {
        float psum[4] = {0.f, 0.f, 0.f, 0.f};
        float pdum[4] = {0.f, 0.f, 0.f, 0.f};
        #pragma unroll
        for (int ct = 0; ct < 4; ++ct) {
            #pragma unroll
            for (int reg = 0; reg < 4; ++reg) {
                const float f = acc[rt][ct][reg] + bsv[ct];
                const int row = n0 + rt * 16 + quad * 4 + reg;
                if (row < N)
                    F[(size_t)row * HO + w * 64 + ct * 16 + c15] = (__bf16)f;
                psum[reg] = fmaf(f, awsv[ct], psum[reg]);
                pdum[reg] = fmaf(f, awdv[ct], pdum[reg]);
            }
        }
        #pragma unroll
        for (int reg = 0; reg < 4; ++reg) {
            float v = psum[reg], u = pdum[reg];
            #pragma unroll
            for (int off = 1; off < 16; off <<= 1) {
                v += __shfl_xor(v, off, 64);
                u += __shfl_xor(u, off, 64);
            }
            const int row = n0 + rt * 16 + quad * 4 + reg;
            if (c15 == 0 && row < N) {
                a_sT[row * H + h] = v;
                a_dT[row * H + h] = u;
            }
        }
    }
}

// ---------------------------------------------------------------------------
// Single-block (1024 thr) exclusive scan of cnt -> row_ptr[0..N]
// ---------------------------------------------------------------------------
__global__ __launch_bounds__(1024) void k_scan(const int* __restrict__ cnt,
                                               int* __restrict__ row_ptr, int N)
{
    __shared__ int wsum[16];
    __shared__ int woff[16];
    const int t = threadIdx.x;
    const int per = (N + 1023) / 1024;
    const int lo = min(t * per, N);
    const int hi = min(lo + per, N);

    int s = 0;
    for (int i = lo; i < hi; ++i) s += cnt[i];

    const int lane = t & 63, w = t >> 6;
    int v = s;
    #pragma unroll
    for (int off = 1; off < 64; off <<= 1) {
        int u = __shfl_up(v, off, 64);
        if (lane >= off) v += u;
    }
    if (lane == 63) wsum[w] = v;
    __syncthreads();
    if (t == 0) {
        int run = 0;
        #pragma unroll
        for (int i = 0; i < 16; ++i) { woff[i] = run; run += wsum[i]; }
    }
    __syncthreads();

    int run = v - s + woff[w];
    for (int i = lo; i < hi; ++i) { row_ptr[i] = run; run += cnt[i]; }
    if (t == 1023) row_ptr[N] = woff[15] + wsum[15];
}

// ---------------------------------------------------------------------------
// Scatter edges into CSR slots, atomic-free: pos = row_ptr[src] + rank[e].
// record = (dst, elem) packed in int2.
// ---------------------------------------------------------------------------
__global__ __launch_bounds__(256) void k_scatter(const int* __restrict__ idx,
    const float* __restrict__ elem, const int* __restrict__ rank,
    const int* __restrict__ row_ptr, int E, int2* __restrict__ csr)
{
    int e = blockIdx.x * 256 + threadIdx.x;
    if (e >= E) return;
    const int s = idx[e];
    const int d = idx[E + e];
    const int pos = row_ptr[s] + rank[e];
    csr[pos] = make_int2(d, __float_as_int(elem[e]));
}

// ---------------------------------------------------------------------------
// Gather: 4 waves/block, one node per wave. Lane owns cols [4L, 4L+4)
// (head h16 = L>>4). Chunk = 64 edges: stage records -> LDS weight pass
// (lane -> edge j=v>>2, head h4=lane&3) -> j-loop with bf16x4 8B F loads.
// ---------------------------------------------------------------------------
__global__ __launch_bounds__(256) void k_gather(const int* __restrict__ row_ptr,
    const int2* __restrict__ csr, const float* __restrict__ a_sT,
    const float* __restrict__ a_dT, const float* __restrict__ aw,
    const float* __restrict__ ab, const __bf16* __restrict__ F,
    float* __restrict__ out, int N)
{
    __shared__ int2  s_rec[4][64];
    __shared__ float s_w[4][256];
    __shared__ int   s_cw[4];

    const int t    = threadIdx.x;
    const int wv   = t >> 6;
    const int lane = t & 63;
    const int n    = blockIdx.x * 4 + wv;
    const int h16  = lane >> 4;   // head for the accumulate loop
    const int h4   = lane & 3;    // head for the weight pass

    int beg = 0, deg = 0;
    if (n < N) { beg = row_ptr[n]; deg = row_ptr[n + 1] - beg; }
    const int cw = (deg + 63) >> 6;
    if (lane == 0) s_cw[wv] = cw;
    __syncthreads();
    const int maxc = max(max(s_cw[0], s_cw[1]), max(s_cw[2], s_cw[3]));

    const float asv = (n < N) ? a_sT[n * H + h4] : 0.f;
    const float awe = aw[h4 * AWS + 2 * O];
    const float abv = ab[h4];

    float4 acc = make_float4(0.f, 0.f, 0.f, 0.f);
    float  rs  = 0.f;

    for (int p = 0; p < maxc; ++p) {
        const int base = beg + p * 64;
        const int cnt  = min(64, deg - p * 64);   // <=0 for finished waves
        const bool act = (p < cw);
        __syncthreads();
        if (act && lane < cnt) s_rec[wv][lane] = csr[base + lane];
        __syncthreads();
        if (act) {
            for (int v = lane; v < cnt * 4; v += 64) {
                const int j = v >> 2;
                const int2 r = s_rec[wv][j];
                const float el = __int_as_float(r.y);
                const float score = asv + a_dT[r.x * H + h4] + awe * el + abv;
                s_w[wv][j * 4 + h4] = __expf(-fmaxf(score * 0.05f, 0.f));
            }
        }
        __syncthreads();
        if (act) {
            for (int j = 0; j < cnt; ++j) {
                const int d = s_rec[wv][j].x;
                const float w = s_w[wv][j * 4 + h16];
                const ushort4 fv = *(const ushort4*)&F[(size_t)d * HO + lane * 4];
                acc.x = fmaf(w, bf2f(fv.x), acc.x);
                acc.y = fmaf(w, bf2f(fv.y), acc.y);
                acc.z = fmaf(w, bf2f(fv.z), acc.z);
                acc.w = fmaf(w, bf2f(fv.w), acc.w);
                rs += w;
            }
        }
    }

    if (n < N) {
        const float inv = 1.f / rs;
        float4 o = make_float4(acc.x * inv, acc.y * inv, acc.z * inv, acc.w * inv);
        *(float4*)&out[(size_t)n * HO + lane * 4] = o;
    }
}

extern "C" void kernel_launch(void* const* d_in, const int* in_sizes, int n_in,
                              void* d_out, int out_size, void* d_ws, size_t ws_size,
                              hipStream_t stream)
{
    const float* x    = (const float*)d_in[0];
    const int*   idx  = (const int*)d_in[1];
    const float* elem = (const float*)d_in[2];
    const float* Ws   = (const float*)d_in[3];
    const float* bs   = (const float*)d_in[4];
    const float* aw   = (const float*)d_in[5];
    const float* ab   = (const float*)d_in[6];

    const int N = in_sizes[0] / DIN;   // 50000
    const int E = in_sizes[1] / 2;     // 800000

    // ws layout: F[N*256]{bf16} | a_sT[N*4] | a_dT[N*4] | cnt[N] |
    //            row_ptr[N+1] | rank[E] | csr[E]{int2} | Bt[256*256]{bf16}
    __bf16* F      = (__bf16*)d_ws;
    float* a_sT    = (float*)(F + (size_t)N * HO);
    float* a_dT    = a_sT + (size_t)N * H;
    int*   cnt     = (int*)(a_dT + (size_t)N * H);
    int*   row_ptr = cnt + N;
    int*   rank    = row_ptr + (N + 1);
    size_t off = (size_t)((char*)(rank + E) - (char*)d_ws);
    off = (off + 7) & ~(size_t)7;
    int2*  csr     = (int2*)((char*)d_ws + off);
    __bf16* Bt     = (__bf16*)(csr + E);
    float* out     = (float*)d_out;

    hipMemsetAsync(cnt, 0, (size_t)N * sizeof(int), stream);

    k_prep_hist<<<256 + (E + 255) / 256, 256, 0, stream>>>(Ws, Bt, idx, E, cnt, rank);
    k_gemm<<<(N + 63) / 64, 256, 0, stream>>>(x, Bt, bs, aw, N, F, a_sT, a_dT);
    k_scan<<<1, 1024, 0, stream>>>(cnt, row_ptr, N);
    k_scatter<<<(E + 255) / 256, 256, 0, stream>>>(idx, elem, rank, row_ptr, E, csr);
    k_gather<<<(N + 3) / 4, 256, 0, stream>>>(row_ptr, csr, a_sT, a_dT, aw, ab,
                                              F, out, N);
}

// Round 6
// 277.568 us; speedup vs baseline: 3.9009x; 1.2267x over previous
//
#include <hip/hip_runtime.h>
#include <math.h>

constexpr int DIN = 256;   // input dim
constexpr int H   = 4;     // heads
constexpr int O   = 64;    // out dim per head
constexpr int HO  = H * O; // 256
constexpr int AWS = 2 * O + 1; // aw row stride = 129

typedef __bf16 bf16x8 __attribute__((ext_vector_type(8)));
typedef float  f32x4  __attribute__((ext_vector_type(4)));

__device__ __forceinline__ float bf2f(unsigned short u) {
    union { unsigned int i; float f; } c;
    c.i = ((unsigned int)u) << 16;
    return c.f;
}

// ---------------------------------------------------------------------------
// Fused prep + hist.
// Blocks [0,256): Bt[n][k] = Ws[h=n>>6][k][o=n&63] as bf16 (256x256).
// Blocks [256, ...): histogram by src; rank[e] = arrival order within src row.
// ---------------------------------------------------------------------------
__global__ __launch_bounds__(256) void k_prep_hist(const float* __restrict__ Ws,
    __bf16* __restrict__ Bt, const int* __restrict__ idx, int E,
    int* __restrict__ cnt, int* __restrict__ rank)
{
    const int b = blockIdx.x;
    if (b < 256) {
        const int i = b * 256 + threadIdx.x;
        const int k = i & 255;
        const int n = i >> 8;
        Bt[n * 256 + k] = (__bf16)Ws[(n >> 6) * (DIN * O) + k * O + (n & 63)];
    } else {
        const int e = (b - 256) * 256 + threadIdx.x;
        if (e < E) rank[e] = atomicAdd(&cnt[idx[e]], 1);
    }
}

// ---------------------------------------------------------------------------
// Kernel 1 (MFMA): F[n,t] = x[n,:] @ Bt[t,:]^T + bs[t], stored as bf16.
// Fused epilogue -> a_sT[n*4+h], a_dT[n*4+h] (fp32).
// ---------------------------------------------------------------------------
__global__ __launch_bounds__(256) void k_gemm(const float* __restrict__ x,
    const __bf16* __restrict__ Bt, const float* __restrict__ bs,
    const float* __restrict__ aw, int N,
    __bf16* __restrict__ F, float* __restrict__ a_sT, float* __restrict__ a_dT)
{
    __shared__ __bf16 As[64][DIN + 8];
    const int t    = threadIdx.x;
    const int w    = t >> 6;          // wave id == head id == col block
    const int lane = t & 63;
    const int c15  = lane & 15;
    const int quad = lane >> 4;
    const int n0   = blockIdx.x * 64;

    #pragma unroll
    for (int i = 0; i < 16; ++i) {
        const int r   = i * 4 + w;
        const int row = n0 + r;
        float4 xv = make_float4(0.f, 0.f, 0.f, 0.f);
        if (row < N) xv = *(const float4*)&x[(size_t)row * DIN + lane * 4];
        __bf16* dst = &As[r][lane * 4];
        dst[0] = (__bf16)xv.x; dst[1] = (__bf16)xv.y;
        dst[2] = (__bf16)xv.z; dst[3] = (__bf16)xv.w;
    }
    __syncthreads();

    f32x4 acc[4][4] = {};
    const __bf16* BtW = Bt + (size_t)(w * 64) * 256;
    const int kq = quad * 8;

    #pragma unroll
    for (int k0 = 0; k0 < DIN; k0 += 32) {
        bf16x8 afr[4], bfr[4];
        #pragma unroll
        for (int rt = 0; rt < 4; ++rt)
            afr[rt] = *(const bf16x8*)&As[rt * 16 + c15][k0 + kq];
        #pragma unroll
        for (int ct = 0; ct < 4; ++ct)
            bfr[ct] = *(const bf16x8*)&BtW[(size_t)(ct * 16 + c15) * 256 + k0 + kq];
        #pragma unroll
        for (int rt = 0; rt < 4; ++rt)
            #pragma unroll
            for (int ct = 0; ct < 4; ++ct)
                acc[rt][ct] = __builtin_amdgcn_mfma_f32_16x16x32_bf16(
                    afr[rt], bfr[ct], acc[rt][ct], 0, 0, 0);
    }

    const int h = w;
    float bsv[4], awsv[4], awdv[4];
    #pragma unroll
    for (int ct = 0; ct < 4; ++ct) {
        const int col = ct * 16 + c15;
        bsv[ct]  = bs[w * 64 + col];
        awsv[ct] = aw[h * AWS + col];
        awdv[ct] = aw[h * AWS + O + col];
    }

    #pragma unroll
    for (int rt = 0; rt < 4; ++rt) {
        float psum[4] = {0.f, 0.f, 0.f, 0.f};
        float pdum[4] = {0.f, 0.f, 0.f, 0.f};
        #pragma unroll
        for (int ct = 0; ct < 4; ++ct) {
            #pragma unroll
            for (int reg = 0; reg < 4; ++reg) {
                const float f = acc[rt][ct][reg] + bsv[ct];
                const int row = n0 + rt * 16 + quad * 4 + reg;
                if (row < N)
                    F[(size_t)row * HO + w * 64 + ct * 16 + c15] = (__bf16)f;
                psum[reg] = fmaf(f, awsv[ct], psum[reg]);
                pdum[reg] = fmaf(f, awdv[ct], pdum[reg]);
            }
        }
        #pragma unroll
        for (int reg = 0; reg < 4; ++reg) {
            float v = psum[reg], u = pdum[reg];
            #pragma unroll
            for (int off = 1; off < 16; off <<= 1) {
                v += __shfl_xor(v, off, 64);
                u += __shfl_xor(u, off, 64);
            }
            const int row = n0 + rt * 16 + quad * 4 + reg;
            if (c15 == 0 && row < N) {
                a_sT[row * H + h] = v;
                a_dT[row * H + h] = u;
            }
        }
    }
}

// ---------------------------------------------------------------------------
// Parallel scan, phase 1: block-local exclusive scan (1 elem/thread) +
// per-block totals.
// ---------------------------------------------------------------------------
__global__ __launch_bounds__(256) void k_scan1(const int* __restrict__ cnt,
    int* __restrict__ row_ptr, int* __restrict__ bsum, int N)
{
    __shared__ int wsum[4], woff[4];
    const int t = threadIdx.x, b = blockIdx.x;
    const int i = b * 256 + t;
    const int lane = t & 63, w = t >> 6;

    const int v = (i < N) ? cnt[i] : 0;
    int s = v;
    #pragma unroll
    for (int off = 1; off < 64; off <<= 1) {
        int u = __shfl_up(s, off, 64);
        if (lane >= off) s += u;
    }
    if (lane == 63) wsum[w] = s;
    __syncthreads();
    if (t == 0) {
        int run = 0;
        #pragma unroll
        for (int j = 0; j < 4; ++j) { woff[j] = run; run += wsum[j]; }
        bsum[b] = run;
    }
    __syncthreads();
    if (i < N) row_ptr[i] = s - v + woff[w];
}

// ---------------------------------------------------------------------------
// Phase 2: single block, exclusive scan of bsum[0..nb) in place; bsum[nb]=total.
// ---------------------------------------------------------------------------
__global__ __launch_bounds__(256) void k_scan2(int* __restrict__ bsum, int nb)
{
    __shared__ int wsum[4], woff[4];
    const int t = threadIdx.x;
    const int lane = t & 63, w = t >> 6;

    const int v = (t < nb) ? bsum[t] : 0;
    int s = v;
    #pragma unroll
    for (int off = 1; off < 64; off <<= 1) {
        int u = __shfl_up(s, off, 64);
        if (lane >= off) s += u;
    }
    if (lane == 63) wsum[w] = s;
    __syncthreads();
    if (t == 0) {
        int run = 0;
        #pragma unroll
        for (int j = 0; j < 4; ++j) { woff[j] = run; run += wsum[j]; }
    }
    __syncthreads();
    const int excl = s - v + woff[w];
    __syncthreads();            // all reads done before in-place writes
    if (t < nb) bsum[t] = excl;
    if (t == 0) bsum[nb] = woff[3] + wsum[3];
}

// ---------------------------------------------------------------------------
// Phase 3: add block offsets; write row_ptr[N].
// ---------------------------------------------------------------------------
__global__ __launch_bounds__(256) void k_scan3(int* __restrict__ row_ptr,
    const int* __restrict__ bsum, int N, int nb)
{
    const int b = blockIdx.x;
    const int i = b * 256 + threadIdx.x;
    if (i < N) row_ptr[i] += bsum[b];
    if (b == 0 && threadIdx.x == 0) row_ptr[N] = bsum[nb];
}

// ---------------------------------------------------------------------------
// Scatter edges into CSR slots, atomic-free: pos = row_ptr[src] + rank[e].
// ---------------------------------------------------------------------------
__global__ __launch_bounds__(256) void k_scatter(const int* __restrict__ idx,
    const float* __restrict__ elem, const int* __restrict__ rank,
    const int* __restrict__ row_ptr, int E, int2* __restrict__ csr)
{
    int e = blockIdx.x * 256 + threadIdx.x;
    if (e >= E) return;
    const int s = idx[e];
    const int d = idx[E + e];
    const int pos = row_ptr[s] + rank[e];
    csr[pos] = make_int2(d, __float_as_int(elem[e]));
}

// ---------------------------------------------------------------------------
// Gather: 4 waves/block, one node per wave. Lane owns cols [4L, 4L+4)
// (head h16 = L>>4). Chunk = 64 edges: stage records -> LDS weight pass
// (lane -> edge j=v>>2, head h4=lane&3) -> j-loop with bf16x4 8B F loads.
// ---------------------------------------------------------------------------
__global__ __launch_bounds__(256) void k_gather(const int* __restrict__ row_ptr,
    const int2* __restrict__ csr, const float* __restrict__ a_sT,
    const float* __restrict__ a_dT, const float* __restrict__ aw,
    const float* __restrict__ ab, const __bf16* __restrict__ F,
    float* __restrict__ out, int N)
{
    __shared__ int2  s_rec[4][64];
    __shared__ float s_w[4][256];
    __shared__ int   s_cw[4];

    const int t    = threadIdx.x;
    const int wv   = t >> 6;
    const int lane = t & 63;
    const int n    = blockIdx.x * 4 + wv;
    const int h16  = lane >> 4;   // head for the accumulate loop
    const int h4   = lane & 3;    // head for the weight pass

    int beg = 0, deg = 0;
    if (n < N) { beg = row_ptr[n]; deg = row_ptr[n + 1] - beg; }
    const int cw = (deg + 63) >> 6;
    if (lane == 0) s_cw[wv] = cw;
    __syncthreads();
    const int maxc = max(max(s_cw[0], s_cw[1]), max(s_cw[2], s_cw[3]));

    const float asv = (n < N) ? a_sT[n * H + h4] : 0.f;
    const float awe = aw[h4 * AWS + 2 * O];
    const float abv = ab[h4];

    float4 acc = make_float4(0.f, 0.f, 0.f, 0.f);
    float  rs  = 0.f;

    for (int p = 0; p < maxc; ++p) {
        const int base = beg + p * 64;
        const int cnt  = min(64, deg - p * 64);
        const bool act = (p < cw);
        __syncthreads();
        if (act && lane < cnt) s_rec[wv][lane] = csr[base + lane];
        __syncthreads();
        if (act) {
            for (int v = lane; v < cnt * 4; v += 64) {
                const int j = v >> 2;
                const int2 r = s_rec[wv][j];
                const float el = __int_as_float(r.y);
                const float score = asv + a_dT[r.x * H + h4] + awe * el + abv;
                s_w[wv][j * 4 + h4] = __expf(-fmaxf(score * 0.05f, 0.f));
            }
        }
        __syncthreads();
        if (act) {
            for (int j = 0; j < cnt; ++j) {
                const int d = s_rec[wv][j].x;
                const float w = s_w[wv][j * 4 + h16];
                const ushort4 fv = *(const ushort4*)&F[(size_t)d * HO + lane * 4];
                acc.x = fmaf(w, bf2f(fv.x), acc.x);
                acc.y = fmaf(w, bf2f(fv.y), acc.y);
                acc.z = fmaf(w, bf2f(fv.z), acc.z);
                acc.w = fmaf(w, bf2f(fv.w), acc.w);
                rs += w;
            }
        }
    }

    if (n < N) {
        const float inv = 1.f / rs;
        float4 o = make_float4(acc.x * inv, acc.y * inv, acc.z * inv, acc.w * inv);
        *(float4*)&out[(size_t)n * HO + lane * 4] = o;
    }
}

extern "C" void kernel_launch(void* const* d_in, const int* in_sizes, int n_in,
                              void* d_out, int out_size, void* d_ws, size_t ws_size,
                              hipStream_t stream)
{
    const float* x    = (const float*)d_in[0];
    const int*   idx  = (const int*)d_in[1];
    const float* elem = (const float*)d_in[2];
    const float* Ws   = (const float*)d_in[3];
    const float* bs   = (const float*)d_in[4];
    const float* aw   = (const float*)d_in[5];
    const float* ab   = (const float*)d_in[6];

    const int N = in_sizes[0] / DIN;   // 50000
    const int E = in_sizes[1] / 2;     // 800000
    const int nb = (N + 255) / 256;    // scan blocks (196)

    // ws layout: F[N*256]{bf16} | a_sT[N*4] | a_dT[N*4] | cnt[N] |
    //            row_ptr[N+1] | rank[E] | bsum[nb+1] | csr[E]{int2} | Bt{bf16}
    __bf16* F      = (__bf16*)d_ws;
    float* a_sT    = (float*)(F + (size_t)N * HO);
    float* a_dT    = a_sT + (size_t)N * H;
    int*   cnt     = (int*)(a_dT + (size_t)N * H);
    int*   row_ptr = cnt + N;
    int*   rank    = row_ptr + (N + 1);
    int*   bsum    = rank + E;
    size_t off = (size_t)((char*)(bsum + nb + 1) - (char*)d_ws);
    off = (off + 7) & ~(size_t)7;
    int2*  csr     = (int2*)((char*)d_ws + off);
    __bf16* Bt     = (__bf16*)(csr + E);
    float* out     = (float*)d_out;

    hipMemsetAsync(cnt, 0, (size_t)N * sizeof(int), stream);

    k_prep_hist<<<256 + (E + 255) / 256, 256, 0, stream>>>(Ws, Bt, idx, E, cnt, rank);
    k_gemm<<<(N + 63) / 64, 256, 0, stream>>>(x, Bt, bs, aw, N, F, a_sT, a_dT);
    k_scan1<<<nb, 256, 0, stream>>>(cnt, row_ptr, bsum, N);
    k_scan2<<<1, 256, 0, stream>>>(bsum, nb);
    k_scan3<<<nb, 256, 0, stream>>>(row_ptr, bsum, N, nb);
    k_scatter<<<(E + 255) / 256, 256, 0, stream>>>(idx, elem, rank, row_ptr, E, csr);
    k_gather<<<(N + 3) / 4, 256, 0, stream>>>(row_ptr, csr, a_sT, a_dT, aw, ab,
                                              F, out, N);
}

// Round 7
// 251.300 us; speedup vs baseline: 4.3087x; 1.1045x over previous
//
#include <hip/hip_runtime.h>
#include <math.h>

constexpr int DIN = 256;   // input dim
constexpr int H   = 4;     // heads
constexpr int O   = 64;    // out dim per head
constexpr int HO  = H * O; // 256
constexpr int AWS = 2 * O + 1; // aw row stride = 129

typedef __bf16 bf16x8 __attribute__((ext_vector_type(8)));
typedef __bf16 bf16x4 __attribute__((ext_vector_type(4)));
typedef float  f32x4  __attribute__((ext_vector_type(4)));

__device__ __forceinline__ float bf2f(unsigned short u) {
    union { unsigned int i; float f; } c;
    c.i = ((unsigned int)u) << 16;
    return c.f;
}

// ---------------------------------------------------------------------------
// Prep: blocks [0,256): Bt[n][k] = Ws[h=n>>6][k][o=n&63] as bf16.
//       blocks [256,452): cnt[i] = 0.
// ---------------------------------------------------------------------------
__global__ __launch_bounds__(256) void k_prep(const float* __restrict__ Ws,
    __bf16* __restrict__ Bt, int* __restrict__ cnt, int N)
{
    const int b = blockIdx.x;
    if (b < 256) {
        const int i = b * 256 + threadIdx.x;
        const int k = i & 255;
        const int n = i >> 8;
        Bt[n * 256 + k] = (__bf16)Ws[(n >> 6) * (DIN * O) + k * O + (n & 63)];
    } else {
        const int i = (b - 256) * 256 + threadIdx.x;
        if (i < N) cnt[i] = 0;
    }
}

// ---------------------------------------------------------------------------
// Merged GEMM + hist. Blocks [0,GB): MFMA gemm row-tile. Blocks [GB,..):
// histogram by src, 4 edges/thread; rank[e] = arrival order in src row.
// ---------------------------------------------------------------------------
__global__ __launch_bounds__(256) void k_gemm_hist(const float* __restrict__ x,
    const __bf16* __restrict__ Bt, const float* __restrict__ bs,
    const float* __restrict__ aw, int N, int GB,
    __bf16* __restrict__ F, float* __restrict__ a_sT, float* __restrict__ a_dT,
    const int* __restrict__ idx, int E, int* __restrict__ cnt,
    int* __restrict__ rank)
{
    __shared__ __bf16 As[64][DIN + 8];
    const int b = blockIdx.x;
    const int t = threadIdx.x;

    if (b >= GB) {   // ---- histogram part ----
        const int base_e = (b - GB) * 1024 + t;
        #pragma unroll
        for (int i = 0; i < 4; ++i) {
            const int e = base_e + i * 256;
            if (e < E) rank[e] = atomicAdd(&cnt[idx[e]], 1);
        }
        return;
    }

    // ---- gemm part ----
    const int w    = t >> 6;          // wave id == head id == col block
    const int lane = t & 63;
    const int c15  = lane & 15;
    const int quad = lane >> 4;
    const int n0   = b * 64;

    #pragma unroll
    for (int i = 0; i < 16; ++i) {
        const int r   = i * 4 + w;
        const int row = n0 + r;
        float4 xv = make_float4(0.f, 0.f, 0.f, 0.f);
        if (row < N) xv = *(const float4*)&x[(size_t)row * DIN + lane * 4];
        bf16x4 pv = { (__bf16)xv.x, (__bf16)xv.y, (__bf16)xv.z, (__bf16)xv.w };
        *(bf16x4*)&As[r][lane * 4] = pv;   // single ds_write_b64
    }
    __syncthreads();

    f32x4 acc[4][4] = {};
    const __bf16* BtW = Bt + (size_t)(w * 64) * 256;
    const int kq = quad * 8;

    #pragma unroll
    for (int k0 = 0; k0 < DIN; k0 += 32) {
        bf16x8 afr[4], bfr[4];
        #pragma unroll
        for (int rt = 0; rt < 4; ++rt)
            afr[rt] = *(const bf16x8*)&As[rt * 16 + c15][k0 + kq];
        #pragma unroll
        for (int ct = 0; ct < 4; ++ct)
            bfr[ct] = *(const bf16x8*)&BtW[(size_t)(ct * 16 + c15) * 256 + k0 + kq];
        #pragma unroll
        for (int rt = 0; rt < 4; ++rt)
            #pragma unroll
            for (int ct = 0; ct < 4; ++ct)
                acc[rt][ct] = __builtin_amdgcn_mfma_f32_16x16x32_bf16(
                    afr[rt], bfr[ct], acc[rt][ct], 0, 0, 0);
    }

    const int h = w;
    float bsv[4], awsv[4], awdv[4];
    #pragma unroll
    for (int ct = 0; ct < 4; ++ct) {
        const int col = ct * 16 + c15;
        bsv[ct]  = bs[w * 64 + col];
        awsv[ct] = aw[h * AWS + col];
        awdv[ct] = aw[h * AWS + O + col];
    }

    #pragma unroll
    for (int rt = 0; rt < 4; ++rt) {
        float psum[4] = {0.f, 0.f, 0.f, 0.f};
        float pdum[4] = {0.f, 0.f, 0.f, 0.f};
        #pragma unroll
        for (int ct = 0; ct < 4; ++ct) {
            #pragma unroll
            for (int reg = 0; reg < 4; ++reg) {
                const float f = acc[rt][ct][reg] + bsv[ct];
                const int row = n0 + rt * 16 + quad * 4 + reg;
                if (row < N)
                    F[(size_t)row * HO + w * 64 + ct * 16 + c15] = (__bf16)f;
                psum[reg] = fmaf(f, awsv[ct], psum[reg]);
                pdum[reg] = fmaf(f, awdv[ct], pdum[reg]);
            }
        }
        #pragma unroll
        for (int reg = 0; reg < 4; ++reg) {
            float v = psum[reg], u = pdum[reg];
            #pragma unroll
            for (int off = 1; off < 16; off <<= 1) {
                v += __shfl_xor(v, off, 64);
                u += __shfl_xor(u, off, 64);
            }
            const int row = n0 + rt * 16 + quad * 4 + reg;
            if (c15 == 0 && row < N) {
                a_sT[row * H + h] = v;
                a_dT[row * H + h] = u;
            }
        }
    }
}

// ---------------------------------------------------------------------------
// Scan phase 1: block-local exclusive scan (1 elem/thread) + block totals.
// Also writes row_ptr[N] (local value; global offset added at use).
// ---------------------------------------------------------------------------
__global__ __launch_bounds__(256) void k_scan1(const int* __restrict__ cnt,
    int* __restrict__ row_ptr, int* __restrict__ bsum, int N)
{
    __shared__ int wsum[4], woff[4];
    const int t = threadIdx.x, b = blockIdx.x;
    const int i = b * 256 + t;
    const int lane = t & 63, w = t >> 6;

    const int v = (i < N) ? cnt[i] : 0;
    int s = v;
    #pragma unroll
    for (int off = 1; off < 64; off <<= 1) {
        int u = __shfl_up(s, off, 64);
        if (lane >= off) s += u;
    }
    if (lane == 63) wsum[w] = s;
    __syncthreads();
    if (t == 0) {
        int run = 0;
        #pragma unroll
        for (int j = 0; j < 4; ++j) { woff[j] = run; run += wsum[j]; }
        bsum[b] = run;
    }
    __syncthreads();
    const int excl = s - v + woff[w];
    if (i < N) row_ptr[i] = excl;
    if (i == N - 1) row_ptr[N] = excl + v;   // local inclusive at end
}

// ---------------------------------------------------------------------------
// Scan phase 2: single block, exclusive scan of bsum[0..nb) in place.
// ---------------------------------------------------------------------------
__global__ __launch_bounds__(256) void k_scan2(int* __restrict__ bsum, int nb)
{
    __shared__ int wsum[4], woff[4];
    const int t = threadIdx.x;
    const int lane = t & 63, w = t >> 6;

    const int v = (t < nb) ? bsum[t] : 0;
    int s = v;
    #pragma unroll
    for (int off = 1; off < 64; off <<= 1) {
        int u = __shfl_up(s, off, 64);
        if (lane >= off) s += u;
    }
    if (lane == 63) wsum[w] = s;
    __syncthreads();
    if (t == 0) {
        int run = 0;
        #pragma unroll
        for (int j = 0; j < 4; ++j) { woff[j] = run; run += wsum[j]; }
    }
    __syncthreads();
    const int excl = s - v + woff[w];
    __syncthreads();
    if (t < nb) bsum[t] = excl;
    if (t == 0) bsum[nb] = woff[3] + wsum[3];
}

// ---------------------------------------------------------------------------
// Scatter, atomic-free: pos = row_ptr[s] + bsum[s>>8] + rank[e].
// ---------------------------------------------------------------------------
__global__ __launch_bounds__(256) void k_scatter(const int* __restrict__ idx,
    const float* __restrict__ elem, const int* __restrict__ rank,
    const int* __restrict__ row_ptr, const int* __restrict__ bsum, int E,
    int2* __restrict__ csr)
{
    int e = blockIdx.x * 256 + threadIdx.x;
    if (e >= E) return;
    const int s = idx[e];
    const int d = idx[E + e];
    const int pos = row_ptr[s] + bsum[s >> 8] + rank[e];
    csr[pos] = make_int2(d, __float_as_int(elem[e]));
}

// ---------------------------------------------------------------------------
// Gather: 4 waves/block, one node per wave, NO block barriers (LDS buffers
// are wave-private; waves are lockstep so a lgkmcnt fence suffices).
// Staging lane j computes all 4 head weights for its edge (float4 a_dT load,
// 4 exps). j-loop unrolled x4 -> 4 independent F-row loads in flight.
// ---------------------------------------------------------------------------
__global__ __launch_bounds__(256) void k_gather(const int* __restrict__ row_ptr,
    const int* __restrict__ bsum, const int2* __restrict__ csr,
    const float* __restrict__ a_sT, const float* __restrict__ a_dT,
    const float* __restrict__ aw, const float* __restrict__ ab,
    const __bf16* __restrict__ F, float* __restrict__ out, int N)
{
    __shared__ int2  s_rec[4][64];
    __shared__ float s_w[4][256];

    const int t    = threadIdx.x;
    const int wv   = t >> 6;
    const int lane = t & 63;
    const int n    = blockIdx.x * 4 + wv;
    if (n >= N) return;                       // whole-wave exit; no barriers
    const int h16  = lane >> 4;

    const int beg = row_ptr[n]     + bsum[n >> 8];
    const int end = row_ptr[n + 1] + bsum[(n + 1) >> 8];

    const float4 as4 = *(const float4*)&a_sT[n * 4];
    const float4 ab4 = *(const float4*)&ab[0];
    const float4 awe4 = make_float4(aw[0 * AWS + 2 * O], aw[1 * AWS + 2 * O],
                                    aw[2 * AWS + 2 * O], aw[3 * AWS + 2 * O]);

    float4 acc = make_float4(0.f, 0.f, 0.f, 0.f);
    float  rs  = 0.f;
    const __bf16* __restrict__ Fl = F + lane * 4;

    for (int base = beg; base < end; base += 64) {
        const int cnt = min(64, end - base);
        if (lane < cnt) {
            const int2 r = csr[base + lane];
            s_rec[wv][lane] = r;
            const float el = __int_as_float(r.y);
            const float4 ad = *(const float4*)&a_dT[r.x * 4];
            float4 w4;
            w4.x = __expf(-fmaxf((as4.x + ad.x + awe4.x * el + ab4.x) * 0.05f, 0.f));
            w4.y = __expf(-fmaxf((as4.y + ad.y + awe4.y * el + ab4.y) * 0.05f, 0.f));
            w4.z = __expf(-fmaxf((as4.z + ad.z + awe4.z * el + ab4.z) * 0.05f, 0.f));
            w4.w = __expf(-fmaxf((as4.w + ad.w + awe4.w * el + ab4.w) * 0.05f, 0.f));
            *(float4*)&s_w[wv][lane * 4] = w4;
        }
        __threadfence_block();   // drain LDS writes; wave lockstep => visible

        int j = 0;
        for (; j + 4 <= cnt; j += 4) {
            const int d0 = s_rec[wv][j + 0].x;
            const int d1 = s_rec[wv][j + 1].x;
            const int d2 = s_rec[wv][j + 2].x;
            const int d3 = s_rec[wv][j + 3].x;
            const float w0 = s_w[wv][(j + 0) * 4 + h16];
            const float w1 = s_w[wv][(j + 1) * 4 + h16];
            const float w2 = s_w[wv][(j + 2) * 4 + h16];
            const float w3 = s_w[wv][(j + 3) * 4 + h16];
            const ushort4 f0 = *(const ushort4*)&Fl[(size_t)d0 * HO];
            const ushort4 f1 = *(const ushort4*)&Fl[(size_t)d1 * HO];
            const ushort4 f2 = *(const ushort4*)&Fl[(size_t)d2 * HO];
            const ushort4 f3 = *(const ushort4*)&Fl[(size_t)d3 * HO];
            acc.x = fmaf(w0, bf2f(f0.x), acc.x);
            acc.y = fmaf(w0, bf2f(f0.y), acc.y);
            acc.z = fmaf(w0, bf2f(f0.z), acc.z);
            acc.w = fmaf(w0, bf2f(f0.w), acc.w);
            acc.x = fmaf(w1, bf2f(f1.x), acc.x);
            acc.y = fmaf(w1, bf2f(f1.y), acc.y);
            acc.z = fmaf(w1, bf2f(f1.z), acc.z);
            acc.w = fmaf(w1, bf2f(f1.w), acc.w);
            acc.x = fmaf(w2, bf2f(f2.x), acc.x);
            acc.y = fmaf(w2, bf2f(f2.y), acc.y);
            acc.z = fmaf(w2, bf2f(f2.z), acc.z);
            acc.w = fmaf(w2, bf2f(f2.w), acc.w);
            acc.x = fmaf(w3, bf2f(f3.x), acc.x);
            acc.y = fmaf(w3, bf2f(f3.y), acc.y);
            acc.z = fmaf(w3, bf2f(f3.z), acc.z);
            acc.w = fmaf(w3, bf2f(f3.w), acc.w);
            rs += w0 + w1 + w2 + w3;
        }
        for (; j < cnt; ++j) {
            const int d = s_rec[wv][j].x;
            const float w = s_w[wv][j * 4 + h16];
            const ushort4 fv = *(const ushort4*)&Fl[(size_t)d * HO];
            acc.x = fmaf(w, bf2f(fv.x), acc.x);
            acc.y = fmaf(w, bf2f(fv.y), acc.y);
            acc.z = fmaf(w, bf2f(fv.z), acc.z);
            acc.w = fmaf(w, bf2f(fv.w), acc.w);
            rs += w;
        }
    }

    const float inv = 1.f / rs;
    float4 o = make_float4(acc.x * inv, acc.y * inv, acc.z * inv, acc.w * inv);
    *(float4*)&out[(size_t)n * HO + lane * 4] = o;
}

extern "C" void kernel_launch(void* const* d_in, const int* in_sizes, int n_in,
                              void* d_out, int out_size, void* d_ws, size_t ws_size,
                              hipStream_t stream)
{
    const float* x    = (const float*)d_in[0];
    const int*   idx  = (const int*)d_in[1];
    const float* elem = (const float*)d_in[2];
    const float* Ws   = (const float*)d_in[3];
    const float* bs   = (const float*)d_in[4];
    const float* aw   = (const float*)d_in[5];
    const float* ab   = (const float*)d_in[6];

    const int N = in_sizes[0] / DIN;   // 50000
    const int E = in_sizes[1] / 2;     // 800000
    const int nb = (N + 255) / 256;    // scan blocks (196)
    const int GB = (N + 63) / 64;      // gemm blocks (782)
    const int HB = (E + 1023) / 1024;  // hist blocks (782)

    // ws layout: F[N*256]{bf16} | a_sT[N*4] | a_dT[N*4] | cnt[N] |
    //            row_ptr[N+1] | rank[E] | bsum[nb+1] | csr[E]{int2} | Bt{bf16}
    __bf16* F      = (__bf16*)d_ws;
    float* a_sT    = (float*)(F + (size_t)N * HO);
    float* a_dT    = a_sT + (size_t)N * H;
    int*   cnt     = (int*)(a_dT + (size_t)N * H);
    int*   row_ptr = cnt + N;
    int*   rank    = row_ptr + (N + 1);
    int*   bsum    = rank + E;
    size_t off = (size_t)((char*)(bsum + nb + 1) - (char*)d_ws);
    off = (off + 7) & ~(size_t)7;
    int2*  csr     = (int2*)((char*)d_ws + off);
    __bf16* Bt     = (__bf16*)(csr + E);
    float* out     = (float*)d_out;

    k_prep<<<256 + nb, 256, 0, stream>>>(Ws, Bt, cnt, N);
    k_gemm_hist<<<GB + HB, 256, 0, stream>>>(x, Bt, bs, aw, N, GB,
                                             F, a_sT, a_dT, idx, E, cnt, rank);
    k_scan1<<<nb, 256, 0, stream>>>(cnt, row_ptr, bsum, N);
    k_scan2<<<1, 256, 0, stream>>>(bsum, nb);
    k_scatter<<<(E + 255) / 256, 256, 0, stream>>>(idx, elem, rank, row_ptr,
                                                   bsum, E, csr);
    k_gather<<<(N + 3) / 4, 256, 0, stream>>>(row_ptr, bsum, csr, a_sT, a_dT,
                                              aw, ab, F, out, N);
}